// Round 2
// baseline (1715.917 us; speedup 1.0000x reference)
//
#include <hip/hip_runtime.h>

#define DI 128

// ---- buf = x (so edge scatter accumulates x + aggr); deg = 0 ----
__global__ __launch_bounds__(256) void k_init(const float4* __restrict__ x,
    float4* __restrict__ buf, unsigned* __restrict__ deg, int N) {
  int idx = blockIdx.x * 256 + threadIdx.x;
  int tot = N * 32;                       // N*128 floats as float4
  if (idx < tot) buf[idx] = x[idx];
  if (idx < N) deg[idx] = 0u;
}

// ---- deg[dst] += 1 per edge ----
__global__ __launch_bounds__(256) void k_count(const int* __restrict__ dst,
    unsigned* __restrict__ deg, int E) {
  int e = blockIdx.x * 256 + threadIdx.x;
  if (e < E) atomicAdd(&deg[dst[e]], 1u);
}

// ---- buf[dst] += x[src], one wave per edge, 2 feats/lane ----
__global__ __launch_bounds__(256) void k_scat1(const float* __restrict__ x,
    const int* __restrict__ src, const int* __restrict__ dst,
    float* __restrict__ buf, int E) {
  int gid = blockIdx.x * 256 + threadIdx.x;
  int e = gid >> 6, lane = gid & 63;
  if (e >= E) return;
  int s = src[e], d = dst[e];
  const float* xs = x + (size_t)s * DI;
  float* bd = buf + (size_t)d * DI;
  atomicAdd(bd + lane,      xs[lane]);
  atomicAdd(bd + lane + 64, xs[lane + 64]);
}

// ---- dinv = rsqrt(deg + 1)  (self-loop makes deg >= 1 always) ----
__global__ __launch_bounds__(256) void k_dinv(const unsigned* __restrict__ deg,
    float* __restrict__ dinv, int N) {
  int i = blockIdx.x * 256 + threadIdx.x;
  if (i < N) dinv[i] = rsqrtf((float)(deg[i] + 1u));
}

// ---- wcat[k][j] = j<64 ? Wmu[k][j] : Wls[k][j-64] ----
__global__ __launch_bounds__(256) void k_wcat(const float* __restrict__ Wmu,
    const float* __restrict__ Wls, float* __restrict__ wcat) {
  int idx = blockIdx.x * 256 + threadIdx.x;  // 128*128
  int k = idx >> 7, j = idx & 127;
  wcat[idx] = (j < 64) ? Wmu[k * 64 + j] : Wls[k * 64 + (j - 64)];
}

// ---- tiled GEMM: out[64-tile,128] = epilogue(A[tile,128] @ W[128,128]) ----
// mode 0: relu(BN(acc + b1))  (p0=b1,p1=gamma,p2=beta,p3=rmean,p4=rvar)
// mode 1: relu(acc + b2)      (p0=b2)
// mode 2: acc                 (no bias; GCN bias added post-aggregation)
// In-place safe: tile rows fully staged to LDS before writeback.
__global__ __launch_bounds__(256) void k_gemm(const float* __restrict__ A,
    const float* __restrict__ W, float* __restrict__ out,
    const float* __restrict__ p0, const float* __restrict__ p1,
    const float* __restrict__ p2, const float* __restrict__ p3,
    const float* __restrict__ p4, int N, int mode) {
  __shared__ float Al[64][129];           // +1 pad: broadcast reads conflict-free
  int t = threadIdx.x;
  int tile0 = blockIdx.x * 64;
  for (int i = t; i < 64 * 32; i += 256) {
    int row = i >> 5, c4 = i & 31;
    int gr = tile0 + row;
    float4 v = make_float4(0.f, 0.f, 0.f, 0.f);
    if (gr < N) v = ((const float4*)A)[gr * 32 + c4];
    int c = c4 * 4;
    Al[row][c] = v.x; Al[row][c + 1] = v.y; Al[row][c + 2] = v.z; Al[row][c + 3] = v.w;
  }
  __syncthreads();

  int ow = t & 15, nw = t >> 4;
  int j0 = ow * 8, n0 = nw * 4;
  float acc[4][8];
#pragma unroll
  for (int i = 0; i < 4; ++i)
#pragma unroll
    for (int j = 0; j < 8; ++j) acc[i][j] = 0.f;

  const float4* Wv = (const float4*)W;
#pragma unroll 4
  for (int k = 0; k < 128; ++k) {
    float4 wA = Wv[k * 32 + (j0 >> 2)];
    float4 wB = Wv[k * 32 + (j0 >> 2) + 1];
    float w[8] = {wA.x, wA.y, wA.z, wA.w, wB.x, wB.y, wB.z, wB.w};
    float a[4] = {Al[n0][k], Al[n0 + 1][k], Al[n0 + 2][k], Al[n0 + 3][k]};
#pragma unroll
    for (int i = 0; i < 4; ++i)
#pragma unroll
      for (int j = 0; j < 8; ++j) acc[i][j] += a[i] * w[j];
  }

  float es[8], eb[8];
  if (mode == 0) {
#pragma unroll
    for (int j = 0; j < 8; ++j) {
      int jj = j0 + j;
      float s = p1[jj] * rsqrtf(p4[jj] + 1e-5f);
      es[j] = s; eb[j] = s * (p0[jj] - p3[jj]) + p2[jj];
    }
  } else if (mode == 1) {
#pragma unroll
    for (int j = 0; j < 8; ++j) { es[j] = 1.f; eb[j] = p0[j0 + j]; }
  } else {
#pragma unroll
    for (int j = 0; j < 8; ++j) { es[j] = 1.f; eb[j] = 0.f; }
  }

#pragma unroll
  for (int i = 0; i < 4; ++i) {
    int gr = tile0 + n0 + i;
    if (gr >= N) continue;
    float o[8];
#pragma unroll
    for (int j = 0; j < 8; ++j) {
      float v = acc[i][j] * es[j] + eb[j];
      if (mode < 2) v = fmaxf(v, 0.f);
      o[j] = v;
    }
    float4* op = (float4*)(out + (size_t)gr * DI + j0);
    op[0] = make_float4(o[0], o[1], o[2], o[3]);
    op[1] = make_float4(o[4], o[5], o[6], o[7]);
  }
}

// ---- out = bias + dinv[i]^2 * xw[i]  (self-loop term + bias init) ----
__global__ __launch_bounds__(256) void k_outinit(const float* __restrict__ xw,
    const float* __restrict__ dinv, const float* __restrict__ bmu,
    const float* __restrict__ bls, float* __restrict__ om,
    float* __restrict__ ol, int N) {
  int idx = blockIdx.x * 256 + threadIdx.x;
  if (idx >= N * 64) return;
  int i = idx >> 6, j = idx & 63;
  float d2 = dinv[i] * dinv[i];
  om[idx] = bmu[j] + d2 * xw[(size_t)i * DI + j];
  ol[idx] = bls[j] + d2 * xw[(size_t)i * DI + 64 + j];
}

// ---- out[dst] += dinv[s]*dinv[d] * xw[src], one wave per edge ----
__global__ __launch_bounds__(256) void k_scat2(const float* __restrict__ xw,
    const int* __restrict__ src, const int* __restrict__ dst,
    const float* __restrict__ dinv, float* __restrict__ om,
    float* __restrict__ ol, int E) {
  int gid = blockIdx.x * 256 + threadIdx.x;
  int e = gid >> 6, lane = gid & 63;
  if (e >= E) return;
  int s = src[e], d = dst[e];
  float nrm = dinv[s] * dinv[d];
  const float* xs = xw + (size_t)s * DI;
  atomicAdd(om + (size_t)d * 64 + lane, nrm * xs[lane]);
  atomicAdd(ol + (size_t)d * 64 + lane, nrm * xs[64 + lane]);
}

extern "C" void kernel_launch(void* const* d_in, const int* in_sizes, int n_in,
                              void* d_out, int out_size, void* d_ws, size_t ws_size,
                              hipStream_t stream) {
  const float* x     = (const float*)d_in[0];
  const int*   ei    = (const int*)d_in[1];
  const float* W1    = (const float*)d_in[2];
  const float* b1    = (const float*)d_in[3];
  const float* gamma = (const float*)d_in[4];
  const float* beta  = (const float*)d_in[5];
  const float* rmean = (const float*)d_in[6];
  const float* rvar  = (const float*)d_in[7];
  const float* W2    = (const float*)d_in[8];
  const float* b2    = (const float*)d_in[9];
  const float* Wmu   = (const float*)d_in[10];
  const float* bmu   = (const float*)d_in[11];
  const float* Wls   = (const float*)d_in[12];
  const float* bls   = (const float*)d_in[13];

  int N = in_sizes[0] / 128;
  int E = in_sizes[1] / 2;
  const int* src = ei;
  const int* dst = ei + E;

  char* ws = (char*)d_ws;
  float*    buf  = (float*)ws;                                    // N*128 f32
  unsigned* deg  = (unsigned*)(ws + (size_t)N * 128 * 4);         // N u32
  float*    dinv = (float*)(ws + (size_t)N * 128 * 4 + (size_t)N * 4);
  float*    wcat = (float*)(ws + (size_t)N * 128 * 4 + (size_t)N * 8);  // 128*128

  float* om = (float*)d_out;
  float* ol = om + (size_t)N * 64;

  int tiles = (N + 63) / 64;

  k_init<<<(N * 32 + 255) / 256, 256, 0, stream>>>((const float4*)x, (float4*)buf, deg, N);
  k_count<<<(E + 255) / 256, 256, 0, stream>>>(dst, deg, E);
  k_scat1<<<(E * 64 + 255) / 256, 256, 0, stream>>>(x, src, dst, buf, E);
  k_dinv<<<(N + 255) / 256, 256, 0, stream>>>(deg, dinv, N);
  k_gemm<<<tiles, 256, 0, stream>>>(buf, W1, buf, b1, gamma, beta, rmean, rvar, N, 0);
  k_gemm<<<tiles, 256, 0, stream>>>(buf, W2, buf, b2, nullptr, nullptr, nullptr, nullptr, N, 1);
  k_wcat<<<64, 256, 0, stream>>>(Wmu, Wls, wcat);
  k_gemm<<<tiles, 256, 0, stream>>>(buf, wcat, buf, nullptr, nullptr, nullptr, nullptr, nullptr, N, 2);
  k_outinit<<<(N * 64 + 255) / 256, 256, 0, stream>>>(buf, dinv, bmu, bls, om, ol, N);
  k_scat2<<<(E * 64 + 255) / 256, 256, 0, stream>>>(buf, src, dst, dinv, om, ol, E);
}

// Round 3
// 870.161 us; speedup vs baseline: 1.9720x; 1.9720x over previous
//
#include <hip/hip_runtime.h>

#define DI 128

// ---- deg = 0 ----
__global__ __launch_bounds__(256) void k_zero(unsigned* __restrict__ deg, int N) {
  int i = blockIdx.x * 256 + threadIdx.x;
  if (i < N) deg[i] = 0u;
}

// ---- deg[dst] += 1 per edge ----
__global__ __launch_bounds__(256) void k_count(const int* __restrict__ dst,
    unsigned* __restrict__ deg, int E) {
  int e = blockIdx.x * 256 + threadIdx.x;
  if (e < E) atomicAdd(&deg[dst[e]], 1u);
}

// ---- block-local exclusive scan of deg; part[i] = local excl, bsum[b] = block total ----
__global__ __launch_bounds__(256) void k_scan1(const unsigned* __restrict__ deg,
    unsigned* __restrict__ part, unsigned* __restrict__ bsum, int N) {
  __shared__ unsigned s[256];
  int tid = threadIdx.x;
  int i = blockIdx.x * 256 + tid;
  unsigned v = (i < N) ? deg[i] : 0u;
  s[tid] = v;
  __syncthreads();
  for (int off = 1; off < 256; off <<= 1) {
    unsigned t = (tid >= off) ? s[tid - off] : 0u;
    __syncthreads();
    s[tid] += t;
    __syncthreads();
  }
  if (i < N) part[i] = s[tid] - v;
  if (tid == 255) bsum[blockIdx.x] = s[255];
}

// ---- single-block exclusive scan of bsum (nb entries, looped) ----
__global__ __launch_bounds__(256) void k_scan2(unsigned* __restrict__ bsum, int nb) {
  __shared__ unsigned s[256];
  __shared__ unsigned carry;
  int tid = threadIdx.x;
  if (tid == 0) carry = 0u;
  __syncthreads();
  for (int base = 0; base < nb; base += 256) {
    int idx = base + tid;
    unsigned c = carry;
    unsigned v = (idx < nb) ? bsum[idx] : 0u;
    s[tid] = v;
    __syncthreads();
    for (int off = 1; off < 256; off <<= 1) {
      unsigned t = (tid >= off) ? s[tid - off] : 0u;
      __syncthreads();
      s[tid] += t;
      __syncthreads();
    }
    if (idx < nb) bsum[idx] = c + s[tid] - v;
    __syncthreads();
    if (tid == 0) carry = c + s[255];
    __syncthreads();
  }
}

// ---- rowptr/cursor = part + bsum[block]; dinv = rsqrt(deg+1) ----
__global__ __launch_bounds__(256) void k_scan3(const unsigned* __restrict__ part,
    const unsigned* __restrict__ bsum, const unsigned* __restrict__ deg,
    unsigned* __restrict__ rowptr, unsigned* __restrict__ cursor,
    float* __restrict__ dinv, int N) {
  int i = blockIdx.x * 256 + threadIdx.x;
  if (i >= N) return;
  unsigned r = part[i] + bsum[i >> 8];
  rowptr[i] = r;
  cursor[i] = r;
  dinv[i] = rsqrtf((float)(deg[i] + 1u));
}

// ---- csr_src[cursor[dst]++] = src ----
__global__ __launch_bounds__(256) void k_fill(const int* __restrict__ src,
    const int* __restrict__ dst, unsigned* __restrict__ cursor,
    int* __restrict__ csr_src, int E) {
  int e = blockIdx.x * 256 + threadIdx.x;
  if (e >= E) return;
  unsigned pos = atomicAdd(&cursor[dst[e]], 1u);
  csr_src[pos] = src[e];
}

// ---- buf[i] = x[i] + sum_{j->i} x[j]   (one wave per node, float2/lane) ----
__global__ __launch_bounds__(256) void k_aggr1(const float* __restrict__ x,
    const unsigned* __restrict__ rowptr, const unsigned* __restrict__ deg,
    const int* __restrict__ csr_src, float* __restrict__ buf, int N) {
  int gid = blockIdx.x * 256 + threadIdx.x;
  int w = gid >> 6, lane = gid & 63;
  if (w >= N) return;
  const float2* xr = (const float2*)(x + (size_t)w * DI);
  float2 acc = xr[lane];
  unsigned start = rowptr[w], cnt = deg[w];
  for (unsigned j = 0; j < cnt; ++j) {
    int s = csr_src[start + j];
    float2 v = ((const float2*)(x + (size_t)s * DI))[lane];
    acc.x += v.x; acc.y += v.y;
  }
  ((float2*)(buf + (size_t)w * DI))[lane] = acc;
}

// ---- wcat[k][j] = j<64 ? Wmu[k][j] : Wls[k][j-64] ----
__global__ __launch_bounds__(256) void k_wcat(const float* __restrict__ Wmu,
    const float* __restrict__ Wls, float* __restrict__ wcat) {
  int idx = blockIdx.x * 256 + threadIdx.x;  // 128*128
  int k = idx >> 7, j = idx & 127;
  wcat[idx] = (j < 64) ? Wmu[k * 64 + j] : Wls[k * 64 + (j - 64)];
}

// ---- tiled GEMM: out[64-tile,128] = epilogue(A[tile,128] @ W[128,128]) ----
// mode 0: relu(BN(acc + b1)); mode 1: relu(acc + b2); mode 2: acc
__global__ __launch_bounds__(256) void k_gemm(const float* __restrict__ A,
    const float* __restrict__ W, float* __restrict__ out,
    const float* __restrict__ p0, const float* __restrict__ p1,
    const float* __restrict__ p2, const float* __restrict__ p3,
    const float* __restrict__ p4, int N, int mode) {
  __shared__ float Al[64][129];
  int t = threadIdx.x;
  int tile0 = blockIdx.x * 64;
  for (int i = t; i < 64 * 32; i += 256) {
    int row = i >> 5, c4 = i & 31;
    int gr = tile0 + row;
    float4 v = make_float4(0.f, 0.f, 0.f, 0.f);
    if (gr < N) v = ((const float4*)A)[gr * 32 + c4];
    int c = c4 * 4;
    Al[row][c] = v.x; Al[row][c + 1] = v.y; Al[row][c + 2] = v.z; Al[row][c + 3] = v.w;
  }
  __syncthreads();

  int ow = t & 15, nw = t >> 4;
  int j0 = ow * 8, n0 = nw * 4;
  float acc[4][8];
#pragma unroll
  for (int i = 0; i < 4; ++i)
#pragma unroll
    for (int j = 0; j < 8; ++j) acc[i][j] = 0.f;

  const float4* Wv = (const float4*)W;
#pragma unroll 4
  for (int k = 0; k < 128; ++k) {
    float4 wA = Wv[k * 32 + (j0 >> 2)];
    float4 wB = Wv[k * 32 + (j0 >> 2) + 1];
    float w[8] = {wA.x, wA.y, wA.z, wA.w, wB.x, wB.y, wB.z, wB.w};
    float a[4] = {Al[n0][k], Al[n0 + 1][k], Al[n0 + 2][k], Al[n0 + 3][k]};
#pragma unroll
    for (int i = 0; i < 4; ++i)
#pragma unroll
      for (int j = 0; j < 8; ++j) acc[i][j] += a[i] * w[j];
  }

  float es[8], eb[8];
  if (mode == 0) {
#pragma unroll
    for (int j = 0; j < 8; ++j) {
      int jj = j0 + j;
      float s = p1[jj] * rsqrtf(p4[jj] + 1e-5f);
      es[j] = s; eb[j] = s * (p0[jj] - p3[jj]) + p2[jj];
    }
  } else if (mode == 1) {
#pragma unroll
    for (int j = 0; j < 8; ++j) { es[j] = 1.f; eb[j] = p0[j0 + j]; }
  } else {
#pragma unroll
    for (int j = 0; j < 8; ++j) { es[j] = 1.f; eb[j] = 0.f; }
  }

#pragma unroll
  for (int i = 0; i < 4; ++i) {
    int gr = tile0 + n0 + i;
    if (gr >= N) continue;
    float o[8];
#pragma unroll
    for (int j = 0; j < 8; ++j) {
      float v = acc[i][j] * es[j] + eb[j];
      if (mode < 2) v = fmaxf(v, 0.f);
      o[j] = v;
    }
    float4* op = (float4*)(out + (size_t)gr * DI + j0);
    op[0] = make_float4(o[0], o[1], o[2], o[3]);
    op[1] = make_float4(o[4], o[5], o[6], o[7]);
  }
}

// ---- GCN heads: out[i] = b + dinv_i^2*xw[i] + sum_{j->i} dinv_j*dinv_i*xw[j] ----
// one wave per node; lane j handles om[j] (feat j) and ol[j] (feat j+64)
__global__ __launch_bounds__(256) void k_aggr2(const float* __restrict__ xw,
    const unsigned* __restrict__ rowptr, const unsigned* __restrict__ deg,
    const int* __restrict__ csr_src, const float* __restrict__ dinv,
    const float* __restrict__ bmu, const float* __restrict__ bls,
    float* __restrict__ om, float* __restrict__ ol, int N) {
  int gid = blockIdx.x * 256 + threadIdx.x;
  int w = gid >> 6, lane = gid & 63;
  if (w >= N) return;
  float di = dinv[w];
  float d2 = di * di;
  const float* xi = xw + (size_t)w * DI;
  float am = bmu[lane] + d2 * xi[lane];
  float al = bls[lane] + d2 * xi[lane + 64];
  unsigned start = rowptr[w], cnt = deg[w];
  for (unsigned j = 0; j < cnt; ++j) {
    int s = csr_src[start + j];
    float nrm = dinv[s] * di;
    const float* xs = xw + (size_t)s * DI;
    am += nrm * xs[lane];
    al += nrm * xs[lane + 64];
  }
  om[(size_t)w * 64 + lane] = am;
  ol[(size_t)w * 64 + lane] = al;
}

extern "C" void kernel_launch(void* const* d_in, const int* in_sizes, int n_in,
                              void* d_out, int out_size, void* d_ws, size_t ws_size,
                              hipStream_t stream) {
  const float* x     = (const float*)d_in[0];
  const int*   ei    = (const int*)d_in[1];
  const float* W1    = (const float*)d_in[2];
  const float* b1    = (const float*)d_in[3];
  const float* gamma = (const float*)d_in[4];
  const float* beta  = (const float*)d_in[5];
  const float* rmean = (const float*)d_in[6];
  const float* rvar  = (const float*)d_in[7];
  const float* W2    = (const float*)d_in[8];
  const float* b2    = (const float*)d_in[9];
  const float* Wmu   = (const float*)d_in[10];
  const float* bmu   = (const float*)d_in[11];
  const float* Wls   = (const float*)d_in[12];
  const float* bls   = (const float*)d_in[13];

  int N = in_sizes[0] / 128;
  int E = in_sizes[1] / 2;
  const int* src = ei;
  const int* dst = ei + E;
  int nb = (N + 255) / 256;

  char* ws = (char*)d_ws;
  size_t off = 0;
  float*    buf     = (float*)(ws + off); off += (size_t)N * DI * 4;
  unsigned* deg     = (unsigned*)(ws + off); off += (size_t)N * 4;
  unsigned* part    = (unsigned*)(ws + off); off += (size_t)N * 4;
  unsigned* rowptr  = (unsigned*)(ws + off); off += (size_t)N * 4;
  unsigned* cursor  = (unsigned*)(ws + off); off += (size_t)N * 4;
  float*    dinv    = (float*)(ws + off); off += (size_t)N * 4;
  unsigned* bsum    = (unsigned*)(ws + off); off += (size_t)((nb + 255) & ~255) * 4;
  float*    wcat    = (float*)(ws + off); off += 128 * 128 * 4;
  int*      csr_src = (int*)(ws + off); off += (size_t)E * 4;

  float* om = (float*)d_out;
  float* ol = om + (size_t)N * 64;

  int tiles = (N + 63) / 64;
  int nodeBlocks = (N * 64 + 255) / 256;

  k_zero <<<nb, 256, 0, stream>>>(deg, N);
  k_count<<<(E + 255) / 256, 256, 0, stream>>>(dst, deg, E);
  k_scan1<<<nb, 256, 0, stream>>>(deg, part, bsum, N);
  k_scan2<<<1, 256, 0, stream>>>(bsum, nb);
  k_scan3<<<nb, 256, 0, stream>>>(part, bsum, deg, rowptr, cursor, dinv, N);
  k_fill <<<(E + 255) / 256, 256, 0, stream>>>(src, dst, cursor, csr_src, E);
  k_aggr1<<<nodeBlocks, 256, 0, stream>>>(x, rowptr, deg, csr_src, buf, N);
  k_gemm <<<tiles, 256, 0, stream>>>(buf, W1, buf, b1, gamma, beta, rmean, rvar, N, 0);
  k_gemm <<<tiles, 256, 0, stream>>>(buf, W2, buf, b2, nullptr, nullptr, nullptr, nullptr, N, 1);
  k_wcat <<<64, 256, 0, stream>>>(Wmu, Wls, wcat);
  k_gemm <<<tiles, 256, 0, stream>>>(buf, wcat, buf, nullptr, nullptr, nullptr, nullptr, nullptr, N, 2);
  k_aggr2<<<nodeBlocks, 256, 0, stream>>>(buf, rowptr, deg, csr_src, dinv, bmu, bls, om, ol, N);
}

// Round 4
// 746.909 us; speedup vs baseline: 2.2974x; 1.1650x over previous
//
#include <hip/hip_runtime.h>

#define DI 128

// ---- deg = 0 ----
__global__ __launch_bounds__(256) void k_zero(unsigned* __restrict__ deg, int N) {
  int i = blockIdx.x * 256 + threadIdx.x;
  if (i < N) deg[i] = 0u;
}

// ---- deg[dst] += 1 per edge ----
__global__ __launch_bounds__(256) void k_count(const int* __restrict__ dst,
    unsigned* __restrict__ deg, int E) {
  int e = blockIdx.x * 256 + threadIdx.x;
  if (e < E) atomicAdd(&deg[dst[e]], 1u);
}

// ---- block-local exclusive scan of deg ----
__global__ __launch_bounds__(256) void k_scan1(const unsigned* __restrict__ deg,
    unsigned* __restrict__ part, unsigned* __restrict__ bsum, int N) {
  __shared__ unsigned s[256];
  int tid = threadIdx.x;
  int i = blockIdx.x * 256 + tid;
  unsigned v = (i < N) ? deg[i] : 0u;
  s[tid] = v;
  __syncthreads();
  for (int off = 1; off < 256; off <<= 1) {
    unsigned t = (tid >= off) ? s[tid - off] : 0u;
    __syncthreads();
    s[tid] += t;
    __syncthreads();
  }
  if (i < N) part[i] = s[tid] - v;
  if (tid == 255) bsum[blockIdx.x] = s[255];
}

// ---- single-block exclusive scan of bsum ----
__global__ __launch_bounds__(256) void k_scan2(unsigned* __restrict__ bsum, int nb) {
  __shared__ unsigned s[256];
  __shared__ unsigned carry;
  int tid = threadIdx.x;
  if (tid == 0) carry = 0u;
  __syncthreads();
  for (int base = 0; base < nb; base += 256) {
    int idx = base + tid;
    unsigned c = carry;
    unsigned v = (idx < nb) ? bsum[idx] : 0u;
    s[tid] = v;
    __syncthreads();
    for (int off = 1; off < 256; off <<= 1) {
      unsigned t = (tid >= off) ? s[tid - off] : 0u;
      __syncthreads();
      s[tid] += t;
      __syncthreads();
    }
    if (idx < nb) bsum[idx] = c + s[tid] - v;
    __syncthreads();
    if (tid == 0) carry = c + s[255];
    __syncthreads();
  }
}

// ---- rowptr/cursor; dinv = rsqrt(deg+1) ----
__global__ __launch_bounds__(256) void k_scan3(const unsigned* __restrict__ part,
    const unsigned* __restrict__ bsum, const unsigned* __restrict__ deg,
    unsigned* __restrict__ rowptr, unsigned* __restrict__ cursor,
    float* __restrict__ dinv, int N) {
  int i = blockIdx.x * 256 + threadIdx.x;
  if (i >= N) return;
  unsigned r = part[i] + bsum[i >> 8];
  rowptr[i] = r;
  cursor[i] = r;
  dinv[i] = rsqrtf((float)(deg[i] + 1u));
}

// ---- csr_src[cursor[dst]++] = src ----
__global__ __launch_bounds__(256) void k_fill(const int* __restrict__ src,
    const int* __restrict__ dst, unsigned* __restrict__ cursor,
    int* __restrict__ csr_src, int E) {
  int e = blockIdx.x * 256 + threadIdx.x;
  if (e >= E) return;
  unsigned pos = atomicAdd(&cursor[dst[e]], 1u);
  csr_src[pos] = src[e];
}

// ---- buf[i] = x[i] + sum_{j->i} x[j]; wave/node, shfl-broadcast idx, 4 accs ----
__global__ __launch_bounds__(256) void k_aggr1(const float* __restrict__ x,
    const unsigned* __restrict__ rowptr, const unsigned* __restrict__ deg,
    const int* __restrict__ csr_src, float* __restrict__ buf, int N) {
  int gid = blockIdx.x * 256 + threadIdx.x;
  int w = gid >> 6, lane = gid & 63;
  if (w >= N) return;
  float2 a0 = ((const float2*)(x + (size_t)w * DI))[lane];
  float2 a1 = {0.f, 0.f}, a2 = {0.f, 0.f}, a3 = {0.f, 0.f};
  unsigned start = rowptr[w];
  int cnt = (int)deg[w];
  for (int base = 0; base < cnt; base += 64) {
    int rem = cnt - base;
    int m = rem < 64 ? rem : 64;
    int idx = 0;
    if (lane < m) idx = csr_src[start + base + lane];
    int j = 0;
    for (; j + 3 < m; j += 4) {
      int s0 = __shfl(idx, j),     s1 = __shfl(idx, j + 1);
      int s2 = __shfl(idx, j + 2), s3 = __shfl(idx, j + 3);
      float2 v0 = ((const float2*)(x + (size_t)s0 * DI))[lane];
      float2 v1 = ((const float2*)(x + (size_t)s1 * DI))[lane];
      float2 v2 = ((const float2*)(x + (size_t)s2 * DI))[lane];
      float2 v3 = ((const float2*)(x + (size_t)s3 * DI))[lane];
      a0.x += v0.x; a0.y += v0.y;  a1.x += v1.x; a1.y += v1.y;
      a2.x += v2.x; a2.y += v2.y;  a3.x += v3.x; a3.y += v3.y;
    }
    for (; j < m; ++j) {
      int s = __shfl(idx, j);
      float2 v = ((const float2*)(x + (size_t)s * DI))[lane];
      a0.x += v.x; a0.y += v.y;
    }
  }
  a0.x += a1.x + a2.x + a3.x;
  a0.y += a1.y + a2.y + a3.y;
  ((float2*)(buf + (size_t)w * DI))[lane] = a0;
}

// ---- fused MLP: out = [relu(relu(BN(A@W1+b1))@W2+b2)] @ [Wmu|Wls]  ----
// 64-row tiles; LDS ping-pong (stride 132 = float4-aligned, conflict-free).
__global__ __launch_bounds__(256, 2) void k_mlp(const float* __restrict__ A,
    const float* __restrict__ W1, const float* __restrict__ b1,
    const float* __restrict__ gamma, const float* __restrict__ beta,
    const float* __restrict__ rmean, const float* __restrict__ rvar,
    const float* __restrict__ W2, const float* __restrict__ b2,
    const float* __restrict__ Wmu, const float* __restrict__ Wls,
    float* __restrict__ out, int N) {
  __shared__ float Ha[64][132];
  __shared__ float Hb[64][132];
  int t = threadIdx.x;
  int tile0 = blockIdx.x * 64;

  // stage A tile
  for (int i = t; i < 64 * 32; i += 256) {
    int row = i >> 5, c4 = i & 31, gr = tile0 + row;
    float4 v = make_float4(0.f, 0.f, 0.f, 0.f);
    if (gr < N) v = ((const float4*)A)[(size_t)gr * 32 + c4];
    *(float4*)&Ha[row][c4 * 4] = v;
  }
  __syncthreads();

  int ow = t & 15, nw = t >> 4;
  int j0 = ow * 8, n0 = nw * 4;
  float acc[4][8];

  auto kloop = [&](const float (*H)[132], const float* W, int ncol4, int jj4) {
#pragma unroll
    for (int i = 0; i < 4; ++i)
#pragma unroll
      for (int j = 0; j < 8; ++j) acc[i][j] = 0.f;
    const float4* Wv = (const float4*)W;
#pragma unroll 4
    for (int k = 0; k < 128; ++k) {
      float4 wA = Wv[k * ncol4 + jj4];
      float4 wB = Wv[k * ncol4 + jj4 + 1];
      float w[8] = {wA.x, wA.y, wA.z, wA.w, wB.x, wB.y, wB.z, wB.w};
      float a[4] = {H[n0][k], H[n0 + 1][k], H[n0 + 2][k], H[n0 + 3][k]};
#pragma unroll
      for (int i = 0; i < 4; ++i)
#pragma unroll
        for (int j = 0; j < 8; ++j) acc[i][j] += a[i] * w[j];
    }
  };

  // ---- layer 1: Ha -> Hb, BN+relu ----
  kloop(Ha, W1, 32, j0 >> 2);
  {
    float es[8], eb[8];
#pragma unroll
    for (int j = 0; j < 8; ++j) {
      int jj = j0 + j;
      float s = gamma[jj] * rsqrtf(rvar[jj] + 1e-5f);
      es[j] = s; eb[j] = s * (b1[jj] - rmean[jj]) + beta[jj];
    }
#pragma unroll
    for (int i = 0; i < 4; ++i)
#pragma unroll
      for (int j = 0; j < 8; ++j)
        Hb[n0 + i][j0 + j] = fmaxf(acc[i][j] * es[j] + eb[j], 0.f);
  }
  __syncthreads();

  // ---- layer 2: Hb -> Ha, +b2, relu ----
  kloop(Hb, W2, 32, j0 >> 2);
#pragma unroll
  for (int i = 0; i < 4; ++i)
#pragma unroll
    for (int j = 0; j < 8; ++j)
      Ha[n0 + i][j0 + j] = fmaxf(acc[i][j] + b2[j0 + j], 0.f);
  __syncthreads();

  // ---- layer 3: Ha -> out (cols 0-63 = Wmu, 64-127 = Wls), no epilogue ----
  const float* Wh = (ow < 8) ? Wmu : Wls;
  kloop(Ha, Wh, 16, (ow & 7) * 2);
#pragma unroll
  for (int i = 0; i < 4; ++i) {
    int gr = tile0 + n0 + i;
    if (gr >= N) continue;
    float4* op = (float4*)(out + (size_t)gr * DI + j0);
    op[0] = make_float4(acc[i][0], acc[i][1], acc[i][2], acc[i][3]);
    op[1] = make_float4(acc[i][4], acc[i][5], acc[i][6], acc[i][7]);
  }
}

// ---- GCN heads gather: out[i] = b + dinv_i^2*xw[i] + sum dinv_s*dinv_i*xw[s] ----
// lane holds feats [2*lane, 2*lane+1]; lane<32 -> mu half, lane>=32 -> ls half
__global__ __launch_bounds__(256) void k_aggr2(const float* __restrict__ xw,
    const unsigned* __restrict__ rowptr, const unsigned* __restrict__ deg,
    const int* __restrict__ csr_src, const float* __restrict__ dinv,
    const float* __restrict__ bmu, const float* __restrict__ bls,
    float* __restrict__ om, float* __restrict__ ol, int N) {
  int gid = blockIdx.x * 256 + threadIdx.x;
  int w = gid >> 6, lane = gid & 63;
  if (w >= N) return;
  float di = dinv[w];
  float d2 = di * di;
  float2 self = ((const float2*)(xw + (size_t)w * DI))[lane];
  float2 bias = (lane < 32) ? ((const float2*)bmu)[lane]
                            : ((const float2*)bls)[lane - 32];
  float2 a0, a1 = {0.f, 0.f}, a2 = {0.f, 0.f}, a3 = {0.f, 0.f};
  a0.x = bias.x + d2 * self.x;
  a0.y = bias.y + d2 * self.y;
  unsigned start = rowptr[w];
  int cnt = (int)deg[w];
  for (int base = 0; base < cnt; base += 64) {
    int rem = cnt - base;
    int m = rem < 64 ? rem : 64;
    int idx = 0; float dv = 0.f;
    if (lane < m) { idx = csr_src[start + base + lane]; dv = dinv[idx]; }
    int j = 0;
    for (; j + 3 < m; j += 4) {
      int s0 = __shfl(idx, j),     s1 = __shfl(idx, j + 1);
      int s2 = __shfl(idx, j + 2), s3 = __shfl(idx, j + 3);
      float n0 = __shfl(dv, j) * di,     n1 = __shfl(dv, j + 1) * di;
      float n2 = __shfl(dv, j + 2) * di, n3 = __shfl(dv, j + 3) * di;
      float2 v0 = ((const float2*)(xw + (size_t)s0 * DI))[lane];
      float2 v1 = ((const float2*)(xw + (size_t)s1 * DI))[lane];
      float2 v2 = ((const float2*)(xw + (size_t)s2 * DI))[lane];
      float2 v3 = ((const float2*)(xw + (size_t)s3 * DI))[lane];
      a0.x += n0 * v0.x; a0.y += n0 * v0.y;
      a1.x += n1 * v1.x; a1.y += n1 * v1.y;
      a2.x += n2 * v2.x; a2.y += n2 * v2.y;
      a3.x += n3 * v3.x; a3.y += n3 * v3.y;
    }
    for (; j < m; ++j) {
      int s = __shfl(idx, j);
      float nn = __shfl(dv, j) * di;
      float2 v = ((const float2*)(xw + (size_t)s * DI))[lane];
      a0.x += nn * v.x; a0.y += nn * v.y;
    }
  }
  a0.x += a1.x + a2.x + a3.x;
  a0.y += a1.y + a2.y + a3.y;
  if (lane < 32)
    ((float2*)(om + (size_t)w * 64))[lane] = a0;
  else
    ((float2*)(ol + (size_t)w * 64))[lane - 32] = a0;
}

extern "C" void kernel_launch(void* const* d_in, const int* in_sizes, int n_in,
                              void* d_out, int out_size, void* d_ws, size_t ws_size,
                              hipStream_t stream) {
  const float* x     = (const float*)d_in[0];
  const int*   ei    = (const int*)d_in[1];
  const float* W1    = (const float*)d_in[2];
  const float* b1    = (const float*)d_in[3];
  const float* gamma = (const float*)d_in[4];
  const float* beta  = (const float*)d_in[5];
  const float* rmean = (const float*)d_in[6];
  const float* rvar  = (const float*)d_in[7];
  const float* W2    = (const float*)d_in[8];
  const float* b2    = (const float*)d_in[9];
  const float* Wmu   = (const float*)d_in[10];
  const float* bmu   = (const float*)d_in[11];
  const float* Wls   = (const float*)d_in[12];
  const float* bls   = (const float*)d_in[13];

  int N = in_sizes[0] / 128;
  int E = in_sizes[1] / 2;
  const int* src = ei;
  const int* dst = ei + E;
  int nb = (N + 255) / 256;

  char* ws = (char*)d_ws;
  size_t off = 0;
  float*    buf     = (float*)(ws + off); off += (size_t)N * DI * 4;
  unsigned* deg     = (unsigned*)(ws + off); off += (size_t)N * 4;
  unsigned* part    = (unsigned*)(ws + off); off += (size_t)N * 4;
  unsigned* rowptr  = (unsigned*)(ws + off); off += (size_t)N * 4;
  unsigned* cursor  = (unsigned*)(ws + off); off += (size_t)N * 4;
  float*    dinv    = (float*)(ws + off); off += (size_t)N * 4;
  unsigned* bsum    = (unsigned*)(ws + off); off += (size_t)((nb + 255) & ~255) * 4;
  int*      csr_src = (int*)(ws + off); off += (size_t)E * 4;

  float* om = (float*)d_out;
  float* ol = om + (size_t)N * 64;

  int tiles = (N + 63) / 64;
  int nodeBlocks = (N * 64 + 255) / 256;

  k_zero <<<nb, 256, 0, stream>>>(deg, N);
  k_count<<<(E + 255) / 256, 256, 0, stream>>>(dst, deg, E);
  k_scan1<<<nb, 256, 0, stream>>>(deg, part, bsum, N);
  k_scan2<<<1, 256, 0, stream>>>(bsum, nb);
  k_scan3<<<nb, 256, 0, stream>>>(part, bsum, deg, rowptr, cursor, dinv, N);
  k_fill <<<(E + 255) / 256, 256, 0, stream>>>(src, dst, cursor, csr_src, E);
  k_aggr1<<<nodeBlocks, 256, 0, stream>>>(x, rowptr, deg, csr_src, buf, N);
  k_mlp  <<<tiles, 256, 0, stream>>>(buf, W1, b1, gamma, beta, rmean, rvar,
                                     W2, b2, Wmu, Wls, buf, N);
  k_aggr2<<<nodeBlocks, 256, 0, stream>>>(buf, rowptr, deg, csr_src, dinv,
                                          bmu, bls, om, ol, N);
}

// Round 5
// 489.954 us; speedup vs baseline: 3.5022x; 1.5244x over previous
//
#include <hip/hip_runtime.h>
#include <hip/hip_bf16.h>

#define DI 128
#define HS 136   // padded LDS stride in bf16 (272B = 17*16B: keeps b128 alignment, staggers banks)

typedef short short8 __attribute__((ext_vector_type(8)));
typedef float f32x4 __attribute__((ext_vector_type(4)));

// ---- deg = 0 ----
__global__ __launch_bounds__(256) void k_zero(unsigned* __restrict__ deg, int N) {
  int i = blockIdx.x * 256 + threadIdx.x;
  if (i < N) deg[i] = 0u;
}

// ---- deg[dst] += 1 ----
__global__ __launch_bounds__(256) void k_count(const int* __restrict__ dst,
    unsigned* __restrict__ deg, int E) {
  int e = blockIdx.x * 256 + threadIdx.x;
  if (e < E) atomicAdd(&deg[dst[e]], 1u);
}

// ---- block-local exclusive scan ----
__global__ __launch_bounds__(256) void k_scan1(const unsigned* __restrict__ deg,
    unsigned* __restrict__ part, unsigned* __restrict__ bsum, int N) {
  __shared__ unsigned s[256];
  int tid = threadIdx.x;
  int i = blockIdx.x * 256 + tid;
  unsigned v = (i < N) ? deg[i] : 0u;
  s[tid] = v;
  __syncthreads();
  for (int off = 1; off < 256; off <<= 1) {
    unsigned t = (tid >= off) ? s[tid - off] : 0u;
    __syncthreads();
    s[tid] += t;
    __syncthreads();
  }
  if (i < N) part[i] = s[tid] - v;
  if (tid == 255) bsum[blockIdx.x] = s[255];
}

// ---- single-block scan of block sums ----
__global__ __launch_bounds__(256) void k_scan2(unsigned* __restrict__ bsum, int nb) {
  __shared__ unsigned s[256];
  __shared__ unsigned carry;
  int tid = threadIdx.x;
  if (tid == 0) carry = 0u;
  __syncthreads();
  for (int base = 0; base < nb; base += 256) {
    int idx = base + tid;
    unsigned c = carry;
    unsigned v = (idx < nb) ? bsum[idx] : 0u;
    s[tid] = v;
    __syncthreads();
    for (int off = 1; off < 256; off <<= 1) {
      unsigned t = (tid >= off) ? s[tid - off] : 0u;
      __syncthreads();
      s[tid] += t;
      __syncthreads();
    }
    if (idx < nb) bsum[idx] = c + s[tid] - v;
    __syncthreads();
    if (tid == 0) carry = c + s[255];
    __syncthreads();
  }
}

// ---- rowptr/cursor; dinv ----
__global__ __launch_bounds__(256) void k_scan3(const unsigned* __restrict__ part,
    const unsigned* __restrict__ bsum, const unsigned* __restrict__ deg,
    unsigned* __restrict__ rowptr, unsigned* __restrict__ cursor,
    float* __restrict__ dinv, int N) {
  int i = blockIdx.x * 256 + threadIdx.x;
  if (i >= N) return;
  unsigned r = part[i] + bsum[i >> 8];
  rowptr[i] = r;
  cursor[i] = r;
  dinv[i] = rsqrtf((float)(deg[i] + 1u));
}

// ---- csr_src[cursor[dst]++] = src ----
__global__ __launch_bounds__(256) void k_fill(const int* __restrict__ src,
    const int* __restrict__ dst, unsigned* __restrict__ cursor,
    int* __restrict__ csr_src, int E) {
  int e = blockIdx.x * 256 + threadIdx.x;
  if (e >= E) return;
  unsigned pos = atomicAdd(&cursor[dst[e]], 1u);
  csr_src[pos] = src[e];
}

// ---- x fp32 -> bf16 (8 elems/thread) ----
__global__ __launch_bounds__(256) void k_cvt(const float4* __restrict__ x4,
    uint4* __restrict__ xb4, int tot8) {
  int i = blockIdx.x * 256 + threadIdx.x;
  if (i >= tot8) return;
  float4 a = x4[2 * i], b = x4[2 * i + 1];
  __hip_bfloat162 p0 = __float22bfloat162_rn(make_float2(a.x, a.y));
  __hip_bfloat162 p1 = __float22bfloat162_rn(make_float2(a.z, a.w));
  __hip_bfloat162 p2 = __float22bfloat162_rn(make_float2(b.x, b.y));
  __hip_bfloat162 p3 = __float22bfloat162_rn(make_float2(b.z, b.w));
  uint4 o;
  o.x = *(unsigned*)&p0; o.y = *(unsigned*)&p1;
  o.z = *(unsigned*)&p2; o.w = *(unsigned*)&p3;
  xb4[i] = o;
}

// ---- weight prep: W1t/W2t/W3t[n][k] = bf16(W[k][n]); W3 = [Wmu | Wls] ----
__global__ __launch_bounds__(256) void k_wprep(const float* __restrict__ W1,
    const float* __restrict__ W2, const float* __restrict__ Wmu,
    const float* __restrict__ Wls, __hip_bfloat16* __restrict__ Wt) {
  int idx = blockIdx.x * 256 + threadIdx.x;      // 3*16384
  if (idx >= 3 * 16384) return;
  int mat = idx >> 14, r = (idx >> 7) & 127, c = idx & 127;  // r=n, c=k
  float v;
  if (mat == 0)      v = W1[c * 128 + r];
  else if (mat == 1) v = W2[c * 128 + r];
  else               v = (r < 64) ? Wmu[c * 64 + r] : Wls[c * 64 + (r - 64)];
  Wt[idx] = __float2bfloat16(v);
}

// ---- aggr1: bufb[i] = bf16( x[i] + sum_{j->i} x[j] ), bf16 in/out, fp32 acc ----
__global__ __launch_bounds__(256) void k_aggr1(const __hip_bfloat162* __restrict__ xb,
    const unsigned* __restrict__ rowptr, const unsigned* __restrict__ deg,
    const int* __restrict__ csr_src, __hip_bfloat162* __restrict__ bufb, int N) {
  int gid = blockIdx.x * 256 + threadIdx.x;
  int w = gid >> 6, lane = gid & 63;
  if (w >= N) return;
  float2 a0 = __bfloat1622float2(xb[(size_t)w * 64 + lane]);
  float2 a1 = {0.f, 0.f}, a2 = {0.f, 0.f}, a3 = {0.f, 0.f};
  unsigned start = rowptr[w];
  int cnt = (int)deg[w];
  for (int base = 0; base < cnt; base += 64) {
    int rem = cnt - base;
    int m = rem < 64 ? rem : 64;
    int idx = 0;
    if (lane < m) idx = csr_src[start + base + lane];
    int j = 0;
    for (; j + 3 < m; j += 4) {
      int s0 = __shfl(idx, j),     s1 = __shfl(idx, j + 1);
      int s2 = __shfl(idx, j + 2), s3 = __shfl(idx, j + 3);
      float2 v0 = __bfloat1622float2(xb[(size_t)s0 * 64 + lane]);
      float2 v1 = __bfloat1622float2(xb[(size_t)s1 * 64 + lane]);
      float2 v2 = __bfloat1622float2(xb[(size_t)s2 * 64 + lane]);
      float2 v3 = __bfloat1622float2(xb[(size_t)s3 * 64 + lane]);
      a0.x += v0.x; a0.y += v0.y;  a1.x += v1.x; a1.y += v1.y;
      a2.x += v2.x; a2.y += v2.y;  a3.x += v3.x; a3.y += v3.y;
    }
    for (; j < m; ++j) {
      int s = __shfl(idx, j);
      float2 v = __bfloat1622float2(xb[(size_t)s * 64 + lane]);
      a0.x += v.x; a0.y += v.y;
    }
  }
  a0.x += a1.x + a2.x + a3.x;
  a0.y += a1.y + a2.y + a3.y;
  bufb[(size_t)w * 64 + lane] = __float22bfloat162_rn(a0);
}

// ---- fused MFMA MLP: h3 = [relu(relu(BN(A@W1))@W2+b2)] @ [Wmu|Wls], bf16 io ----
// 64-row tile, 4 waves; wave handles rows 16w..16w+15, 8 n-tiles of 16.
__global__ __launch_bounds__(256, 3) void k_mlp(const __hip_bfloat16* __restrict__ Ab,
    const __hip_bfloat16* __restrict__ Wt3,   // 3 x [128][128] bf16, [n][k]
    const float* __restrict__ b1, const float* __restrict__ gamma,
    const float* __restrict__ beta, const float* __restrict__ rmean,
    const float* __restrict__ rvar, const float* __restrict__ b2,
    __hip_bfloat16* __restrict__ outb, int N) {
  __shared__ __hip_bfloat16 H[64][HS];
  __shared__ __hip_bfloat16 Wt[128][HS];
  int t = threadIdx.x;
  int tile0 = blockIdx.x * 64;
  int lane = t & 63, wave = t >> 6;
  int m16 = lane & 15, quad = lane >> 4;

  // stage A tile: 4 threads/row, 64B (32 bf16) each
  {
    int row = t >> 2, c0 = (t & 3) * 32;
    int gr = tile0 + row;
    uint4 z = {0u, 0u, 0u, 0u};
    const uint4* gp = (const uint4*)(Ab + (size_t)gr * DI + c0);
#pragma unroll
    for (int i = 0; i < 4; ++i) {
      uint4 v = (gr < N) ? gp[i] : z;
      *(uint4*)&H[row][c0 + i * 8] = v;
    }
  }

  f32x4 acc[8];
  short8 aF[4];

  for (int l = 0; l < 3; ++l) {
    // stage this layer's Wt: 2 threads/row, 128B each
    {
      int n = t >> 1, c0 = (t & 1) * 64;
      const uint4* gp = (const uint4*)(Wt3 + (size_t)l * 16384 + (size_t)n * 128 + c0);
#pragma unroll
      for (int i = 0; i < 8; ++i)
        *(uint4*)&Wt[n][c0 + i * 8] = gp[i];
    }
    __syncthreads();

    // fragments + MFMA
#pragma unroll
    for (int ks = 0; ks < 4; ++ks)
      aF[ks] = *(const short8*)&H[wave * 16 + m16][ks * 32 + quad * 8];
#pragma unroll
    for (int nt = 0; nt < 8; ++nt) {
      f32x4 c = {0.f, 0.f, 0.f, 0.f};
#pragma unroll
      for (int ks = 0; ks < 4; ++ks) {
        short8 bF = *(const short8*)&Wt[nt * 16 + m16][ks * 32 + quad * 8];
        c = __builtin_amdgcn_mfma_f32_16x16x32_bf16(aF[ks], bF, c, 0, 0, 0);
      }
      acc[nt] = c;
    }
    __syncthreads();   // all reads of H/Wt done

    // epilogue: C/D layout col=lane&15 (=n within tile), row=quad*4+reg
#pragma unroll
    for (int nt = 0; nt < 8; ++nt) {
      int n = nt * 16 + m16;
      float es = 1.f, eb = 0.f;
      if (l == 0) {
        float s = gamma[n] * rsqrtf(rvar[n] + 1e-5f);
        es = s; eb = s * (b1[n] - rmean[n]) + beta[n];
      } else if (l == 1) {
        eb = b2[n];
      }
#pragma unroll
      for (int r = 0; r < 4; ++r) {
        float v = acc[nt][r] * es + eb;
        if (l < 2) v = fmaxf(v, 0.f);
        H[wave * 16 + quad * 4 + r][n] = __float2bfloat16(v);
      }
    }
  }
  __syncthreads();

  // cooperative coalesced writeback of h3
  {
    int row = t >> 2, c0 = (t & 3) * 32;
    int gr = tile0 + row;
    if (gr < N) {
      uint4* gp = (uint4*)(outb + (size_t)gr * DI + c0);
#pragma unroll
      for (int i = 0; i < 4; ++i)
        gp[i] = *(const uint4*)&H[row][c0 + i * 8];
    }
  }
}

// ---- GCN heads gather (bf16 xw, fp32 out) ----
__global__ __launch_bounds__(256) void k_aggr2(const __hip_bfloat162* __restrict__ xw,
    const unsigned* __restrict__ rowptr, const unsigned* __restrict__ deg,
    const int* __restrict__ csr_src, const float* __restrict__ dinv,
    const float* __restrict__ bmu, const float* __restrict__ bls,
    float* __restrict__ om, float* __restrict__ ol, int N) {
  int gid = blockIdx.x * 256 + threadIdx.x;
  int w = gid >> 6, lane = gid & 63;
  if (w >= N) return;
  float di = dinv[w];
  float d2 = di * di;
  float2 self = __bfloat1622float2(xw[(size_t)w * 64 + lane]);
  float2 bias = (lane < 32) ? ((const float2*)bmu)[lane]
                            : ((const float2*)bls)[lane - 32];
  float2 a0, a1 = {0.f, 0.f}, a2 = {0.f, 0.f}, a3 = {0.f, 0.f};
  a0.x = bias.x + d2 * self.x;
  a0.y = bias.y + d2 * self.y;
  unsigned start = rowptr[w];
  int cnt = (int)deg[w];
  for (int base = 0; base < cnt; base += 64) {
    int rem = cnt - base;
    int m = rem < 64 ? rem : 64;
    int idx = 0; float dv = 0.f;
    if (lane < m) { idx = csr_src[start + base + lane]; dv = dinv[idx]; }
    int j = 0;
    for (; j + 3 < m; j += 4) {
      int s0 = __shfl(idx, j),     s1 = __shfl(idx, j + 1);
      int s2 = __shfl(idx, j + 2), s3 = __shfl(idx, j + 3);
      float n0 = __shfl(dv, j) * di,     n1 = __shfl(dv, j + 1) * di;
      float n2 = __shfl(dv, j + 2) * di, n3 = __shfl(dv, j + 3) * di;
      float2 v0 = __bfloat1622float2(xw[(size_t)s0 * 64 + lane]);
      float2 v1 = __bfloat1622float2(xw[(size_t)s1 * 64 + lane]);
      float2 v2 = __bfloat1622float2(xw[(size_t)s2 * 64 + lane]);
      float2 v3 = __bfloat1622float2(xw[(size_t)s3 * 64 + lane]);
      a0.x += n0 * v0.x; a0.y += n0 * v0.y;
      a1.x += n1 * v1.x; a1.y += n1 * v1.y;
      a2.x += n2 * v2.x; a2.y += n2 * v2.y;
      a3.x += n3 * v3.x; a3.y += n3 * v3.y;
    }
    for (; j < m; ++j) {
      int s = __shfl(idx, j);
      float nn = __shfl(dv, j) * di;
      float2 v = __bfloat1622float2(xw[(size_t)s * 64 + lane]);
      a0.x += nn * v.x; a0.y += nn * v.y;
    }
  }
  a0.x += a1.x + a2.x + a3.x;
  a0.y += a1.y + a2.y + a3.y;
  if (lane < 32)
    ((float2*)(om + (size_t)w * 64))[lane] = a0;
  else
    ((float2*)(ol + (size_t)w * 64))[lane - 32] = a0;
}

extern "C" void kernel_launch(void* const* d_in, const int* in_sizes, int n_in,
                              void* d_out, int out_size, void* d_ws, size_t ws_size,
                              hipStream_t stream) {
  const float* x     = (const float*)d_in[0];
  const int*   ei    = (const int*)d_in[1];
  const float* W1    = (const float*)d_in[2];
  const float* b1    = (const float*)d_in[3];
  const float* gamma = (const float*)d_in[4];
  const float* beta  = (const float*)d_in[5];
  const float* rmean = (const float*)d_in[6];
  const float* rvar  = (const float*)d_in[7];
  const float* W2    = (const float*)d_in[8];
  const float* b2    = (const float*)d_in[9];
  const float* Wmu   = (const float*)d_in[10];
  const float* bmu   = (const float*)d_in[11];
  const float* Wls   = (const float*)d_in[12];
  const float* bls   = (const float*)d_in[13];

  int N = in_sizes[0] / 128;
  int E = in_sizes[1] / 2;
  const int* src = ei;
  const int* dst = ei + E;
  int nb = (N + 255) / 256;

  char* ws = (char*)d_ws;
  size_t off = 0;
  __hip_bfloat16* xb   = (__hip_bfloat16*)(ws + off); off += (size_t)N * DI * 2;  // also reused as h3
  __hip_bfloat16* bufb = (__hip_bfloat16*)(ws + off); off += (size_t)N * DI * 2;
  unsigned* deg    = (unsigned*)(ws + off); off += (size_t)N * 4;
  unsigned* part   = (unsigned*)(ws + off); off += (size_t)N * 4;
  unsigned* rowptr = (unsigned*)(ws + off); off += (size_t)N * 4;
  unsigned* cursor = (unsigned*)(ws + off); off += (size_t)N * 4;
  float*    dinv   = (float*)(ws + off); off += (size_t)N * 4;
  unsigned* bsum   = (unsigned*)(ws + off); off += (size_t)((nb + 255) & ~255) * 4;
  __hip_bfloat16* Wt3 = (__hip_bfloat16*)(ws + off); off += 3 * 16384 * 2;
  int* csr_src = (int*)(ws + off); off += (size_t)E * 4;

  float* om = (float*)d_out;
  float* ol = om + (size_t)N * 64;

  int tiles = (N + 63) / 64;
  int nodeBlocks = (N * 64 + 255) / 256;
  int tot8 = N * 16;

  k_zero <<<nb, 256, 0, stream>>>(deg, N);
  k_count<<<(E + 255) / 256, 256, 0, stream>>>(dst, deg, E);
  k_cvt  <<<(tot8 + 255) / 256, 256, 0, stream>>>((const float4*)x, (uint4*)xb, tot8);
  k_wprep<<<192, 256, 0, stream>>>(W1, W2, Wmu, Wls, Wt3);
  k_scan1<<<nb, 256, 0, stream>>>(deg, part, bsum, N);
  k_scan2<<<1, 256, 0, stream>>>(bsum, nb);
  k_scan3<<<nb, 256, 0, stream>>>(part, bsum, deg, rowptr, cursor, dinv, N);
  k_fill <<<(E + 255) / 256, 256, 0, stream>>>(src, dst, cursor, csr_src, E);
  k_aggr1<<<nodeBlocks, 256, 0, stream>>>((const __hip_bfloat162*)xb, rowptr, deg,
                                          csr_src, (__hip_bfloat162*)bufb, N);
  k_mlp  <<<tiles, 256, 0, stream>>>(bufb, Wt3, b1, gamma, beta, rmean, rvar, b2,
                                     xb /* h3 out, reuse */, N);
  k_aggr2<<<nodeBlocks, 256, 0, stream>>>((const __hip_bfloat162*)xb, rowptr, deg,
                                          csr_src, dinv, bmu, bls, om, ol, N);
}

// Round 6
// 409.981 us; speedup vs baseline: 4.1854x; 1.1951x over previous
//
#include <hip/hip_runtime.h>
#include <hip/hip_bf16.h>

#define DI 128
#define HS 136   // padded LDS stride in bf16 (272B = 17*16B: keeps b128 alignment, staggers banks)

typedef short short8 __attribute__((ext_vector_type(8)));
typedef float f32x4 __attribute__((ext_vector_type(4)));

// ---- deg = 0 ----
__global__ __launch_bounds__(256) void k_zero(unsigned* __restrict__ deg, int N) {
  int i = blockIdx.x * 256 + threadIdx.x;
  if (i < N) deg[i] = 0u;
}

// ---- deg[dst] += 1; rank[e] = old value (edge's slot within its dst row) ----
__global__ __launch_bounds__(256) void k_count(const int* __restrict__ dst,
    unsigned* __restrict__ deg, unsigned* __restrict__ rank, int E) {
  int e = blockIdx.x * 256 + threadIdx.x;
  if (e < E) rank[e] = atomicAdd(&deg[dst[e]], 1u);
}

// ---- block-local exclusive scan ----
__global__ __launch_bounds__(256) void k_scan1(const unsigned* __restrict__ deg,
    unsigned* __restrict__ part, unsigned* __restrict__ bsum, int N) {
  __shared__ unsigned s[256];
  int tid = threadIdx.x;
  int i = blockIdx.x * 256 + tid;
  unsigned v = (i < N) ? deg[i] : 0u;
  s[tid] = v;
  __syncthreads();
  for (int off = 1; off < 256; off <<= 1) {
    unsigned t = (tid >= off) ? s[tid - off] : 0u;
    __syncthreads();
    s[tid] += t;
    __syncthreads();
  }
  if (i < N) part[i] = s[tid] - v;
  if (tid == 255) bsum[blockIdx.x] = s[255];
}

// ---- single-block scan of block sums ----
__global__ __launch_bounds__(256) void k_scan2(unsigned* __restrict__ bsum, int nb) {
  __shared__ unsigned s[256];
  __shared__ unsigned carry;
  int tid = threadIdx.x;
  if (tid == 0) carry = 0u;
  __syncthreads();
  for (int base = 0; base < nb; base += 256) {
    int idx = base + tid;
    unsigned c = carry;
    unsigned v = (idx < nb) ? bsum[idx] : 0u;
    s[tid] = v;
    __syncthreads();
    for (int off = 1; off < 256; off <<= 1) {
      unsigned t = (tid >= off) ? s[tid - off] : 0u;
      __syncthreads();
      s[tid] += t;
      __syncthreads();
    }
    if (idx < nb) bsum[idx] = c + s[tid] - v;
    __syncthreads();
    if (tid == 0) carry = c + s[255];
    __syncthreads();
  }
}

// ---- rowptr; dinv ----
__global__ __launch_bounds__(256) void k_scan3(const unsigned* __restrict__ part,
    const unsigned* __restrict__ bsum, const unsigned* __restrict__ deg,
    unsigned* __restrict__ rowptr, float* __restrict__ dinv, int N) {
  int i = blockIdx.x * 256 + threadIdx.x;
  if (i >= N) return;
  rowptr[i] = part[i] + bsum[i >> 8];
  dinv[i] = rsqrtf((float)(deg[i] + 1u));
}

// ---- dst-partitioned CSR fill (no atomics): csr_src[rowptr[d]+rank[e]] = src[e] ----
// partition p = blockIdx&7 owns dst range [p*span,(p+1)*span); its csr slice
// (~800KB) stays hot in L2 so 64B lines fill completely before writeback.
__global__ __launch_bounds__(256) void k_fillp(const int* __restrict__ src,
    const int* __restrict__ dst, const unsigned* __restrict__ rank,
    const unsigned* __restrict__ rowptr, int* __restrict__ csr_src, int E, int N) {
  int p = blockIdx.x & 7;
  int b = blockIdx.x >> 3;
  int nbp = gridDim.x >> 3;
  int span = (N + 7) >> 3;
  int lo = p * span;
  int hi = lo + span; if (hi > N) hi = N;
  int chunk = (E + nbp - 1) / nbp;
  int e0 = b * chunk;
  int e1 = e0 + chunk; if (e1 > E) e1 = E;
  for (int e = e0 + threadIdx.x; e < e1; e += 256) {
    int d = dst[e];
    if (d >= lo && d < hi)
      csr_src[rowptr[d] + rank[e]] = src[e];
  }
}

// ---- x fp32 -> bf16 (8 elems/thread) ----
__global__ __launch_bounds__(256) void k_cvt(const float4* __restrict__ x4,
    uint4* __restrict__ xb4, int tot8) {
  int i = blockIdx.x * 256 + threadIdx.x;
  if (i >= tot8) return;
  float4 a = x4[2 * i], b = x4[2 * i + 1];
  __hip_bfloat162 p0 = __float22bfloat162_rn(make_float2(a.x, a.y));
  __hip_bfloat162 p1 = __float22bfloat162_rn(make_float2(a.z, a.w));
  __hip_bfloat162 p2 = __float22bfloat162_rn(make_float2(b.x, b.y));
  __hip_bfloat162 p3 = __float22bfloat162_rn(make_float2(b.z, b.w));
  uint4 o;
  o.x = *(unsigned*)&p0; o.y = *(unsigned*)&p1;
  o.z = *(unsigned*)&p2; o.w = *(unsigned*)&p3;
  xb4[i] = o;
}

// ---- weight prep: Wt[n][k] = bf16(W[k][n]); W3 = [Wmu | Wls] ----
__global__ __launch_bounds__(256) void k_wprep(const float* __restrict__ W1,
    const float* __restrict__ W2, const float* __restrict__ Wmu,
    const float* __restrict__ Wls, __hip_bfloat16* __restrict__ Wt) {
  int idx = blockIdx.x * 256 + threadIdx.x;      // 3*16384
  if (idx >= 3 * 16384) return;
  int mat = idx >> 14, r = (idx >> 7) & 127, c = idx & 127;  // r=n, c=k
  float v;
  if (mat == 0)      v = W1[c * 128 + r];
  else if (mat == 1) v = W2[c * 128 + r];
  else               v = (r < 64) ? Wmu[c * 64 + r] : Wls[c * 64 + (r - 64)];
  Wt[idx] = __float2bfloat16(v);
}

// ---- aggr1: bufb[i] = bf16( x[i] + sum_{j->i} x[j] ); 8 loads in flight ----
__global__ __launch_bounds__(256) void k_aggr1(const __hip_bfloat162* __restrict__ xb,
    const unsigned* __restrict__ rowptr, const unsigned* __restrict__ deg,
    const int* __restrict__ csr_src, __hip_bfloat162* __restrict__ bufb, int N) {
  int gid = blockIdx.x * 256 + threadIdx.x;
  int w = gid >> 6, lane = gid & 63;
  if (w >= N) return;
  float2 a[8];
  a[0] = __bfloat1622float2(xb[(size_t)w * 64 + lane]);
#pragma unroll
  for (int i = 1; i < 8; ++i) a[i] = make_float2(0.f, 0.f);
  unsigned start = rowptr[w];
  int cnt = (int)deg[w];
  for (int base = 0; base < cnt; base += 64) {
    int rem = cnt - base;
    int m = rem < 64 ? rem : 64;
    int idx = 0;
    if (lane < m) idx = csr_src[start + base + lane];
    int j = 0;
    for (; j + 7 < m; j += 8) {
      float2 v[8];
#pragma unroll
      for (int u = 0; u < 8; ++u) {
        int s = __shfl(idx, j + u);
        v[u] = __bfloat1622float2(xb[(size_t)s * 64 + lane]);
      }
#pragma unroll
      for (int u = 0; u < 8; ++u) { a[u].x += v[u].x; a[u].y += v[u].y; }
    }
    for (; j < m; ++j) {
      int s = __shfl(idx, j);
      float2 v = __bfloat1622float2(xb[(size_t)s * 64 + lane]);
      a[0].x += v.x; a[0].y += v.y;
    }
  }
#pragma unroll
  for (int i = 1; i < 8; ++i) { a[0].x += a[i].x; a[0].y += a[i].y; }
  bufb[(size_t)w * 64 + lane] = __float22bfloat162_rn(a[0]);
}

// ---- fused MFMA MLP: h3 = [relu(relu(BN(A@W1))@W2+b2)] @ [Wmu|Wls], bf16 io ----
__global__ __launch_bounds__(256, 3) void k_mlp(const __hip_bfloat16* __restrict__ Ab,
    const __hip_bfloat16* __restrict__ Wt3,   // 3 x [128][128] bf16, [n][k]
    const float* __restrict__ b1, const float* __restrict__ gamma,
    const float* __restrict__ beta, const float* __restrict__ rmean,
    const float* __restrict__ rvar, const float* __restrict__ b2,
    __hip_bfloat16* __restrict__ outb, int N) {
  __shared__ __hip_bfloat16 H[64][HS];
  __shared__ __hip_bfloat16 Wt[128][HS];
  int t = threadIdx.x;
  int tile0 = blockIdx.x * 64;
  int lane = t & 63, wave = t >> 6;
  int m16 = lane & 15, quad = lane >> 4;

  {
    int row = t >> 2, c0 = (t & 3) * 32;
    int gr = tile0 + row;
    uint4 z = {0u, 0u, 0u, 0u};
    const uint4* gp = (const uint4*)(Ab + (size_t)gr * DI + c0);
#pragma unroll
    for (int i = 0; i < 4; ++i) {
      uint4 v = (gr < N) ? gp[i] : z;
      *(uint4*)&H[row][c0 + i * 8] = v;
    }
  }

  f32x4 acc[8];
  short8 aF[4];

  for (int l = 0; l < 3; ++l) {
    {
      int n = t >> 1, c0 = (t & 1) * 64;
      const uint4* gp = (const uint4*)(Wt3 + (size_t)l * 16384 + (size_t)n * 128 + c0);
#pragma unroll
      for (int i = 0; i < 8; ++i)
        *(uint4*)&Wt[n][c0 + i * 8] = gp[i];
    }
    __syncthreads();

#pragma unroll
    for (int ks = 0; ks < 4; ++ks)
      aF[ks] = *(const short8*)&H[wave * 16 + m16][ks * 32 + quad * 8];
#pragma unroll
    for (int nt = 0; nt < 8; ++nt) {
      f32x4 c = {0.f, 0.f, 0.f, 0.f};
#pragma unroll
      for (int ks = 0; ks < 4; ++ks) {
        short8 bF = *(const short8*)&Wt[nt * 16 + m16][ks * 32 + quad * 8];
        c = __builtin_amdgcn_mfma_f32_16x16x32_bf16(aF[ks], bF, c, 0, 0, 0);
      }
      acc[nt] = c;
    }
    __syncthreads();

#pragma unroll
    for (int nt = 0; nt < 8; ++nt) {
      int n = nt * 16 + m16;
      float es = 1.f, eb = 0.f;
      if (l == 0) {
        float s = gamma[n] * rsqrtf(rvar[n] + 1e-5f);
        es = s; eb = s * (b1[n] - rmean[n]) + beta[n];
      } else if (l == 1) {
        eb = b2[n];
      }
#pragma unroll
      for (int r = 0; r < 4; ++r) {
        float v = acc[nt][r] * es + eb;
        if (l < 2) v = fmaxf(v, 0.f);
        H[wave * 16 + quad * 4 + r][n] = __float2bfloat16(v);
      }
    }
  }
  __syncthreads();

  {
    int row = t >> 2, c0 = (t & 3) * 32;
    int gr = tile0 + row;
    if (gr < N) {
      uint4* gp = (uint4*)(outb + (size_t)gr * DI + c0);
#pragma unroll
      for (int i = 0; i < 4; ++i)
        gp[i] = *(const uint4*)&H[row][c0 + i * 8];
    }
  }
}

// ---- GCN heads gather (bf16 xw, fp32 out); 8 loads in flight ----
__global__ __launch_bounds__(256) void k_aggr2(const __hip_bfloat162* __restrict__ xw,
    const unsigned* __restrict__ rowptr, const unsigned* __restrict__ deg,
    const int* __restrict__ csr_src, const float* __restrict__ dinv,
    const float* __restrict__ bmu, const float* __restrict__ bls,
    float* __restrict__ om, float* __restrict__ ol, int N) {
  int gid = blockIdx.x * 256 + threadIdx.x;
  int w = gid >> 6, lane = gid & 63;
  if (w >= N) return;
  float di = dinv[w];
  float d2 = di * di;
  float2 self = __bfloat1622float2(xw[(size_t)w * 64 + lane]);
  float2 bias = (lane < 32) ? ((const float2*)bmu)[lane]
                            : ((const float2*)bls)[lane - 32];
  float2 a[8];
  a[0].x = bias.x + d2 * self.x;
  a[0].y = bias.y + d2 * self.y;
#pragma unroll
  for (int i = 1; i < 8; ++i) a[i] = make_float2(0.f, 0.f);
  unsigned start = rowptr[w];
  int cnt = (int)deg[w];
  for (int base = 0; base < cnt; base += 64) {
    int rem = cnt - base;
    int m = rem < 64 ? rem : 64;
    int idx = 0; float dv = 0.f;
    if (lane < m) { idx = csr_src[start + base + lane]; dv = dinv[idx]; }
    int j = 0;
    for (; j + 7 < m; j += 8) {
      float2 v[8]; float nn[8];
#pragma unroll
      for (int u = 0; u < 8; ++u) {
        int s = __shfl(idx, j + u);
        nn[u] = __shfl(dv, j + u) * di;
        v[u] = __bfloat1622float2(xw[(size_t)s * 64 + lane]);
      }
#pragma unroll
      for (int u = 0; u < 8; ++u) {
        a[u].x += nn[u] * v[u].x; a[u].y += nn[u] * v[u].y;
      }
    }
    for (; j < m; ++j) {
      int s = __shfl(idx, j);
      float nn = __shfl(dv, j) * di;
      float2 v = __bfloat1622float2(xw[(size_t)s * 64 + lane]);
      a[0].x += nn * v.x; a[0].y += nn * v.y;
    }
  }
#pragma unroll
  for (int i = 1; i < 8; ++i) { a[0].x += a[i].x; a[0].y += a[i].y; }
  if (lane < 32)
    ((float2*)(om + (size_t)w * 64))[lane] = a[0];
  else
    ((float2*)(ol + (size_t)w * 64))[lane - 32] = a[0];
}

extern "C" void kernel_launch(void* const* d_in, const int* in_sizes, int n_in,
                              void* d_out, int out_size, void* d_ws, size_t ws_size,
                              hipStream_t stream) {
  const float* x     = (const float*)d_in[0];
  const int*   ei    = (const int*)d_in[1];
  const float* W1    = (const float*)d_in[2];
  const float* b1    = (const float*)d_in[3];
  const float* gamma = (const float*)d_in[4];
  const float* beta  = (const float*)d_in[5];
  const float* rmean = (const float*)d_in[6];
  const float* rvar  = (const float*)d_in[7];
  const float* W2    = (const float*)d_in[8];
  const float* b2    = (const float*)d_in[9];
  const float* Wmu   = (const float*)d_in[10];
  const float* bmu   = (const float*)d_in[11];
  const float* Wls   = (const float*)d_in[12];
  const float* bls   = (const float*)d_in[13];

  int N = in_sizes[0] / 128;
  int E = in_sizes[1] / 2;
  const int* src = ei;
  const int* dst = ei + E;
  int nb = (N + 255) / 256;

  char* ws = (char*)d_ws;
  size_t off = 0;
  __hip_bfloat16* xb   = (__hip_bfloat16*)(ws + off); off += (size_t)N * DI * 2;  // reused as h3
  __hip_bfloat16* bufb = (__hip_bfloat16*)(ws + off); off += (size_t)N * DI * 2;
  unsigned* deg    = (unsigned*)(ws + off); off += (size_t)N * 4;
  unsigned* part   = (unsigned*)(ws + off); off += (size_t)N * 4;
  unsigned* rowptr = (unsigned*)(ws + off); off += (size_t)N * 4;
  float*    dinv   = (float*)(ws + off); off += (size_t)N * 4;
  unsigned* bsum   = (unsigned*)(ws + off); off += (size_t)((nb + 255) & ~255) * 4;
  __hip_bfloat16* Wt3 = (__hip_bfloat16*)(ws + off); off += 3 * 16384 * 2;
  unsigned* rank   = (unsigned*)(ws + off); off += (size_t)E * 4;
  int* csr_src     = (int*)(ws + off); off += (size_t)E * 4;

  float* om = (float*)d_out;
  float* ol = om + (size_t)N * 64;

  int tiles = (N + 63) / 64;
  int nodeBlocks = (N * 64 + 255) / 256;
  int tot8 = N * 16;

  k_zero <<<nb, 256, 0, stream>>>(deg, N);
  k_count<<<(E + 255) / 256, 256, 0, stream>>>(dst, deg, rank, E);
  k_cvt  <<<(tot8 + 255) / 256, 256, 0, stream>>>((const float4*)x, (uint4*)xb, tot8);
  k_wprep<<<192, 256, 0, stream>>>(W1, W2, Wmu, Wls, Wt3);
  k_scan1<<<nb, 256, 0, stream>>>(deg, part, bsum, N);
  k_scan2<<<1, 256, 0, stream>>>(bsum, nb);
  k_scan3<<<nb, 256, 0, stream>>>(part, bsum, deg, rowptr, dinv, N);
  k_fillp<<<2048, 256, 0, stream>>>(src, dst, rank, rowptr, csr_src, E, N);
  k_aggr1<<<nodeBlocks, 256, 0, stream>>>((const __hip_bfloat162*)xb, rowptr, deg,
                                          csr_src, (__hip_bfloat162*)bufb, N);
  k_mlp  <<<tiles, 256, 0, stream>>>(bufb, Wt3, b1, gamma, beta, rmean, rvar, b2,
                                     xb /* h3 out, reuse */, N);
  k_aggr2<<<nodeBlocks, 256, 0, stream>>>((const __hip_bfloat162*)xb, rowptr, deg,
                                          csr_src, dinv, bmu, bls, om, ol, N);
}